// Round 8
// baseline (290.648 us; speedup 1.0000x reference)
//
#include <hip/hip_runtime.h>
#include <stdint.h>

#define N_NODES 100000
#define CH 128
#define K_NEIGH 16
#define TN 32          // k_main node tile: 100000/32 = 3125 exact
#define XT_STRIDE 36   // k_main X tile stride
#define XS_STRIDE 68   // legacy kernel only
#define PS 132         // pivot stride (node-major [n][o])

#define PSWZ(n, o) ((n) * PS + ((o) ^ ((((n) >> 3) & 3) << 3)))

// ============================================================================
// Round 16. r7 evidence: k_main unchanged 132us; k_w2x_mfma ~113us vs ~15us
// floor -> staging/latency-bound (falsifier fired). Changes:
//  * k_w2x_mfma: __launch_bounds__(256,2) -> (256,4). 32KB LDS x4 = 128KB
//    fits; ~112 VGPR fits 128. 2x TLP to hide staging + ds_read->MFMA chains.
//  * k_main: gather pair-unroll -- 2 nodes, 32 independent 8B loads in
//    flight, js read lazily as int4 broadcasts (stay under 64-VGPR cap).
//  * everything else r7-identical (audited).
// ============================================================================

typedef short bf8v __attribute__((ext_vector_type(8)));   // 8 bf16 = 4 VGPR
typedef float f32x4 __attribute__((ext_vector_type(4)));

__device__ __forceinline__ uint32_t pack_bf16x2(float a, float b) {
    union { float f; uint32_t u; } ua, ub;
    ua.f = a; ub.f = b;
    const uint32_t ra = (ua.u + 0x7fffu + ((ua.u >> 16) & 1u)) >> 16;
    const uint32_t rb = (ub.u + 0x7fffu + ((ub.u >> 16) & 1u)) >> 16;
    return ra | (rb << 16);
}
__device__ __forceinline__ uint16_t bf16_rne(float f) {
    union { float f; uint32_t u; } c; c.f = f;
    return (uint16_t)((c.u + 0x7fffu + ((c.u >> 16) & 1u)) >> 16);
}
__device__ __forceinline__ float bf16_tof(uint16_t h) {
    union { uint32_t u; float f; } c; c.u = ((uint32_t)h) << 16; return c.f;
}
__device__ __forceinline__ float bf16_lo(uint32_t u) {
    union { uint32_t u; float f; } c; c.u = u << 16; return c.f;
}
__device__ __forceinline__ float bf16_hi(uint32_t u) {
    union { uint32_t u; float f; } c; c.u = u & 0xffff0000u; return c.f;
}

// ---------------------------------------------------------------------------
// Pre-kernel: W2 -> (hi, lo) bf16 planes. 16384 elements.
// ---------------------------------------------------------------------------
__global__ void k_wcvt(const float* __restrict__ W,
                       uint16_t* __restrict__ Wh, uint16_t* __restrict__ Wl) {
    const int i = blockIdx.x * 256 + threadIdx.x;
    if (i < CH * CH) {
        const float f = W[i];
        const uint16_t h = bf16_rne(f);
        Wh[i] = h;
        Wl[i] = bf16_rne(f - bf16_tof(h));
    }
}

// ---------------------------------------------------------------------------
// Kernel 1: Yt[N][CH] = bf16((W2 @ X)^T) via MFMA 16x16x32 bf16, hi/lo split.
// 64-node tile, 4 waves; wave w owns o in [32w, 32w+32). 4 blocks/CU.
// ---------------------------------------------------------------------------
__global__ __launch_bounds__(256, 4) void k_w2x_mfma(
    const float*    __restrict__ X,    // [C][N] f32
    const uint16_t* __restrict__ W2h,  // [o][c] bf16 hi
    const uint16_t* __restrict__ W2l,  // [o][c] bf16 lo
    uint16_t*       __restrict__ Yt)   // [N][CH] bf16
{
    __shared__ __align__(16) uint16_t XsH[64 * 128];  // 16 KB
    __shared__ __align__(16) uint16_t XsL[64 * 128];  // 16 KB

    const int t  = threadIdx.x;
    const int n0 = blockIdx.x * 64;
    const int V  = (N_NODES - n0 < 64) ? (N_NODES - n0) : 64;

    // ---- stage X: load f32 coalesced, split hi/lo, transposed swizzled ----
    for (int it = 0; it < 8; ++it) {
        const int idx = t + it * 256;          // 0..2047
        const int nq = idx & 15, c = idx >> 4; // 16 float4-cols, 128 c-rows
        float4 v = make_float4(0.f, 0.f, 0.f, 0.f);
        if (nq * 4 < V)
            v = *(const float4*)&X[(size_t)c * N_NODES + n0 + nq * 4];
        const float vv0 = v.x, vv1 = v.y, vv2 = v.z, vv3 = v.w;
#pragma unroll
        for (int s = 0; s < 4; ++s) {
            const float f = (s == 0) ? vv0 : (s == 1) ? vv1 : (s == 2) ? vv2 : vv3;
            const int n = nq * 4 + s;
            const uint16_t h = bf16_rne(f);
            const uint16_t lo = bf16_rne(f - bf16_tof(h));
            const int byi = (n << 8) + (((c * 2)) ^ ((n & 7) << 4));
            XsH[byi >> 1] = h;
            XsL[byi >> 1] = lo;
        }
    }

    // ---- A-frags: W2 hi/lo, loaded once (contiguous dwordx4 per frag) ----
    const int l = t & 63;
    const int w = t >> 6;                 // wave id 0..3
    bf8v ah[2][4], al[2][4];
    const int ar = l & 15;                // A row within 16-tile
    const int ac = (l >> 4) * 8;          // A k-offset
#pragma unroll
    for (int ot = 0; ot < 2; ++ot)
#pragma unroll
        for (int ks = 0; ks < 4; ++ks) {
            const size_t off = (size_t)(w * 32 + ot * 16 + ar) * CH + ks * 32 + ac;
            ah[ot][ks] = *(const bf8v*)&W2h[off];
            al[ot][ks] = *(const bf8v*)&W2l[off];
        }
    __syncthreads();

    // ---- MFMA: D[o][n], 2 o-tiles x 4 n-tiles, K=128 in 4 steps ----
    f32x4 d[2][4];
#pragma unroll
    for (int ot = 0; ot < 2; ++ot)
#pragma unroll
        for (int nt = 0; nt < 4; ++nt)
            d[ot][nt] = (f32x4){0.f, 0.f, 0.f, 0.f};

#pragma unroll
    for (int ks = 0; ks < 4; ++ks) {
#pragma unroll
        for (int nt = 0; nt < 4; ++nt) {
            const int n  = nt * 16 + (l & 15);
            const int byi = (n << 8) + ((ks * 64 + ((l >> 4) * 16)) ^ ((n & 7) << 4));
            const bf8v bh = *(const bf8v*)((const char*)XsH + byi);
            const bf8v bl = *(const bf8v*)((const char*)XsL + byi);
#pragma unroll
            for (int ot = 0; ot < 2; ++ot) {
                d[ot][nt] = __builtin_amdgcn_mfma_f32_16x16x32_bf16(
                    ah[ot][ks], bh, d[ot][nt], 0, 0, 0);
                d[ot][nt] = __builtin_amdgcn_mfma_f32_16x16x32_bf16(
                    al[ot][ks], bh, d[ot][nt], 0, 0, 0);
                d[ot][nt] = __builtin_amdgcn_mfma_f32_16x16x32_bf16(
                    ah[ot][ks], bl, d[ot][nt], 0, 0, 0);
            }
        }
    }

    // ---- store: lane holds o = base+(l>>4)*4+r, n = nt*16+(l&15) ----
#pragma unroll
    for (int ot = 0; ot < 2; ++ot)
#pragma unroll
        for (int nt = 0; nt < 4; ++nt) {
            const int n = nt * 16 + (l & 15);
            if (n < V) {
                const int o4 = w * 32 + ot * 16 + (l >> 4) * 4;
                uint2 pv;
                pv.x = pack_bf16x2(d[ot][nt][0], d[ot][nt][1]);
                pv.y = pack_bf16x2(d[ot][nt][2], d[ot][nt][3]);
                *(uint2*)&Yt[(size_t)(n0 + n) * CH + o4] = pv;
            }
        }
}

// ---------------------------------------------------------------------------
// Kernel 2: Out = W1@X + mean_k bf16(Yt)[adj] + biases. 32-node tile,
// 8 blocks/CU. Gather: 2-node pair unroll, 32 independent 8B loads in flight.
// ---------------------------------------------------------------------------
__global__ __launch_bounds__(256, 8) void k_main(
    const float*    __restrict__ X,    // [C][N] f32
    const int*      __restrict__ adj,  // [N][K] int32
    const float*    __restrict__ W1,   // [o][c] f32
    const float*    __restrict__ B1,
    const float*    __restrict__ B2,
    const uint16_t* __restrict__ Yt,   // [N][CH] bf16
    float*          __restrict__ Out)  // [O][N] f32
{
    __shared__ __align__(16) float Xs[CH * XT_STRIDE];
    __shared__ __align__(16) int adjS[TN * K_NEIGH];

    const int t  = threadIdx.x;
    const int n0 = blockIdx.x * TN;

    if (t < 128)
        *(int4*)&adjS[t * 4] = *(const int4*)&adj[(size_t)n0 * K_NEIGH + t * 4];
    for (int it = 0; it < 4; ++it) {
        const int idx = t + it * 256;
        const int nq = idx & 7, c = idx >> 3;
        *(float4*)&Xs[c * XT_STRIDE + nq * 4] =
            *(const float4*)&X[(size_t)c * N_NODES + n0 + nq * 4];
    }
    __syncthreads();

    const int ng = t & 7, og = t >> 3;
    float acc[4][4];
#pragma unroll
    for (int i = 0; i < 4; ++i)
#pragma unroll
        for (int j = 0; j < 4; ++j) acc[i][j] = 0.0f;

    const float* wp = W1 + (size_t)(og * 4) * CH;
#pragma unroll 1
    for (int c0 = 0; c0 < CH; c0 += 4) {
        float4 wq[4];
#pragma unroll
        for (int i = 0; i < 4; ++i)
            wq[i] = *(const float4*)&wp[i * CH + c0];
#pragma unroll
        for (int e = 0; e < 4; ++e) {
            const float4 xv = *(const float4*)&Xs[(c0 + e) * XT_STRIDE + ng * 4];
#pragma unroll
            for (int i = 0; i < 4; ++i) {
                const float w = ((const float*)&wq[i])[e];
                acc[i][0] = fmaf(w, xv.x, acc[i][0]);
                acc[i][1] = fmaf(w, xv.y, acc[i][1]);
                acc[i][2] = fmaf(w, xv.z, acc[i][2]);
                acc[i][3] = fmaf(w, xv.w, acc[i][3]);
            }
        }
    }

    __syncthreads();
    float* P = Xs;
#pragma unroll
    for (int j = 0; j < 4; ++j) {
        const int n = ng * 4 + j;
        float4 v = make_float4(acc[0][j], acc[1][j], acc[2][j], acc[3][j]);
        *(float4*)&P[PSWZ(n, og * 4)] = v;
    }
    __syncthreads();

    // ---- gather-mean from bf16 Yt, RMW into P; 2-node pairs ----
    // group g (32 lanes) handles nodes {g, 8+g} then {16+g, 24+g};
    // lane l owns channels 4l..4l+3 (uint2 = 8B). js via int4 broadcasts.
    {
        const int l4 = (t & 31) * 4;
        const int g  = t >> 5;
#pragma unroll
        for (int itp = 0; itp < 2; ++itp) {
            const int nA = itp * 16 + g;
            const int nB = nA + 8;
            float4 aA0 = make_float4(0.f, 0.f, 0.f, 0.f);
            float4 aA1 = make_float4(0.f, 0.f, 0.f, 0.f);
            float4 aB0 = make_float4(0.f, 0.f, 0.f, 0.f);
            float4 aB1 = make_float4(0.f, 0.f, 0.f, 0.f);
#pragma unroll
            for (int k = 0; k < K_NEIGH; k += 4) {
                const int4 jA = *(const int4*)&adjS[nA * K_NEIGH + k];
                const int4 jB = *(const int4*)&adjS[nB * K_NEIGH + k];
                const uint2 vA0 = *(const uint2*)&Yt[(size_t)jA.x * CH + l4];
                const uint2 vA1 = *(const uint2*)&Yt[(size_t)jA.y * CH + l4];
                const uint2 vA2 = *(const uint2*)&Yt[(size_t)jA.z * CH + l4];
                const uint2 vA3 = *(const uint2*)&Yt[(size_t)jA.w * CH + l4];
                const uint2 vB0 = *(const uint2*)&Yt[(size_t)jB.x * CH + l4];
                const uint2 vB1 = *(const uint2*)&Yt[(size_t)jB.y * CH + l4];
                const uint2 vB2 = *(const uint2*)&Yt[(size_t)jB.z * CH + l4];
                const uint2 vB3 = *(const uint2*)&Yt[(size_t)jB.w * CH + l4];
                aA0.x += bf16_lo(vA0.x); aA0.y += bf16_hi(vA0.x);
                aA0.z += bf16_lo(vA0.y); aA0.w += bf16_hi(vA0.y);
                aA1.x += bf16_lo(vA1.x); aA1.y += bf16_hi(vA1.x);
                aA1.z += bf16_lo(vA1.y); aA1.w += bf16_hi(vA1.y);
                aA0.x += bf16_lo(vA2.x); aA0.y += bf16_hi(vA2.x);
                aA0.z += bf16_lo(vA2.y); aA0.w += bf16_hi(vA2.y);
                aA1.x += bf16_lo(vA3.x); aA1.y += bf16_hi(vA3.x);
                aA1.z += bf16_lo(vA3.y); aA1.w += bf16_hi(vA3.y);
                aB0.x += bf16_lo(vB0.x); aB0.y += bf16_hi(vB0.x);
                aB0.z += bf16_lo(vB0.y); aB0.w += bf16_hi(vB0.y);
                aB1.x += bf16_lo(vB1.x); aB1.y += bf16_hi(vB1.x);
                aB1.z += bf16_lo(vB1.y); aB1.w += bf16_hi(vB1.y);
                aB0.x += bf16_lo(vB2.x); aB0.y += bf16_hi(vB2.x);
                aB0.z += bf16_lo(vB2.y); aB0.w += bf16_hi(vB2.y);
                aB1.x += bf16_lo(vB3.x); aB1.y += bf16_hi(vB3.x);
                aB1.z += bf16_lo(vB3.y); aB1.w += bf16_hi(vB3.y);
            }
            float4 cA = *(const float4*)&P[PSWZ(nA, l4)];
            cA.x += (aA0.x + aA1.x) * 0.0625f;
            cA.y += (aA0.y + aA1.y) * 0.0625f;
            cA.z += (aA0.z + aA1.z) * 0.0625f;
            cA.w += (aA0.w + aA1.w) * 0.0625f;
            *(float4*)&P[PSWZ(nA, l4)] = cA;
            float4 cB = *(const float4*)&P[PSWZ(nB, l4)];
            cB.x += (aB0.x + aB1.x) * 0.0625f;
            cB.y += (aB0.y + aB1.y) * 0.0625f;
            cB.z += (aB0.z + aB1.z) * 0.0625f;
            cB.w += (aB0.w + aB1.w) * 0.0625f;
            *(float4*)&P[PSWZ(nB, l4)] = cB;
        }
    }
    __syncthreads();

    for (int it = 0; it < 4; ++it) {
        const int idx = t + it * 256;
        const int o = idx >> 3, nq = idx & 7;
        const float bb = B1[o] + B2[o];
        float4 v;
        v.x = P[PSWZ(nq * 4 + 0, o)] + bb;
        v.y = P[PSWZ(nq * 4 + 1, o)] + bb;
        v.z = P[PSWZ(nq * 4 + 2, o)] + bb;
        v.w = P[PSWZ(nq * 4 + 3, o)] + bb;
        *(float4*)&Out[(size_t)o * N_NODES + n0 + nq * 4] = v;
    }
}

// ---------------------------------------------------------------------------
// Legacy fused kernel (audited) -- fallback if workspace too small.
// ---------------------------------------------------------------------------
__global__ __launch_bounds__(256, 2) void k_fused_legacy(
    const float* __restrict__ X,
    const int*   __restrict__ adj,
    const float* __restrict__ W1,
    const float* __restrict__ B1,
    const float* __restrict__ W2,
    const float* __restrict__ B2,
    float*       __restrict__ Out)
{
    __shared__ __align__(16) float Xs[CH * XS_STRIDE];
    __shared__ __align__(16) float As[CH * XS_STRIDE];
    __shared__ int adjS[64 * K_NEIGH];

    const int t  = threadIdx.x;
    const int n0 = blockIdx.x * 64;
    const int V  = (N_NODES - n0 < 64) ? (N_NODES - n0) : 64;

    {
        const int base  = n0 * K_NEIGH;
        const int valid = V * K_NEIGH;
        for (int idx = t; idx < 64 * K_NEIGH; idx += 256)
            adjS[idx] = (idx < valid) ? adj[base + idx] : 0;
    }
    for (int it = 0; it < 32; ++it) {
        const int idx = t + it * 256;
        const int n = idx & 63, c = idx >> 6;
        Xs[c * XS_STRIDE + n] =
            (n < V) ? X[(size_t)c * N_NODES + n0 + n] : 0.0f;
    }
    __syncthreads();

    {
        const int n_l = t & 63, q = t >> 6;
        int js[K_NEIGH];
#pragma unroll
        for (int k = 0; k < K_NEIGH; ++k) js[k] = adjS[n_l * K_NEIGH + k];
        if (n_l < V) {
            for (int cc = 0; cc < 32; ++cc) {
                const int c = q * 32 + cc;
                const float* xc = X + (size_t)c * N_NODES;
                float s = 0.0f;
#pragma unroll
                for (int k = 0; k < K_NEIGH; ++k) s += xc[js[k]];
                As[c * XS_STRIDE + n_l] = s * 0.0625f;
            }
        } else {
            for (int cc = 0; cc < 32; ++cc)
                As[(q * 32 + cc) * XS_STRIDE + n_l] = 0.0f;
        }
    }
    __syncthreads();

    const int ng = t & 7, og = t >> 3;
    float acc[4][8];
#pragma unroll
    for (int i = 0; i < 4; ++i)
#pragma unroll
        for (int j = 0; j < 8; ++j) acc[i][j] = 0.0f;

    const float* w1p = W1 + (og * 4) * CH;
    const float* w2p = W2 + (og * 4) * CH;
    for (int c = 0; c < CH; ++c) {
        float xv[8], av[8], w1v[4], w2v[4];
        *(float4*)&xv[0] = *(const float4*)&Xs[c * XS_STRIDE + ng * 8];
        *(float4*)&xv[4] = *(const float4*)&Xs[c * XS_STRIDE + ng * 8 + 4];
        *(float4*)&av[0] = *(const float4*)&As[c * XS_STRIDE + ng * 8];
        *(float4*)&av[4] = *(const float4*)&As[c * XS_STRIDE + ng * 8 + 4];
#pragma unroll
        for (int i = 0; i < 4; ++i) {
            w1v[i] = w1p[i * CH + c];
            w2v[i] = w2p[i * CH + c];
        }
#pragma unroll
        for (int i = 0; i < 4; ++i)
#pragma unroll
            for (int j = 0; j < 8; ++j)
                acc[i][j] += w1v[i] * xv[j] + w2v[i] * av[j];
    }

    __syncthreads();
    float* Zt = Xs;
#pragma unroll
    for (int i = 0; i < 4; ++i) {
        *(float4*)&Zt[(og * 4 + i) * XS_STRIDE + ng * 8]     = *(float4*)&acc[i][0];
        *(float4*)&Zt[(og * 4 + i) * XS_STRIDE + ng * 8 + 4] = *(float4*)&acc[i][4];
    }
    __syncthreads();
    for (int it = 0; it < 32; ++it) {
        const int idx = t + it * 256;
        const int n = idx & 63, o = idx >> 6;
        if (n < V) {
            Out[(size_t)o * N_NODES + n0 + n] =
                Zt[o * XS_STRIDE + n] + B1[o] + B2[o];
        }
    }
}

extern "C" void kernel_launch(void* const* d_in, const int* in_sizes, int n_in,
                              void* d_out, int out_size, void* d_ws, size_t ws_size,
                              hipStream_t stream) {
    const float* X   = (const float*)d_in[0];
    const int*   adj = (const int*)d_in[1];
    const float* W1  = (const float*)d_in[2];
    const float* B1  = (const float*)d_in[3];
    const float* W2  = (const float*)d_in[4];
    const float* B2  = (const float*)d_in[5];
    float* Out = (float*)d_out;

    const size_t yt_bytes = (size_t)N_NODES * CH * sizeof(uint16_t);  // 25.6 MB
    const size_t w_bytes  = (size_t)CH * CH * sizeof(uint16_t);       // 32 KB
    const size_t need     = yt_bytes + 2 * w_bytes;

    if (ws_size >= need) {
        uint16_t* Yt  = (uint16_t*)d_ws;
        uint16_t* W2h = Yt + (size_t)N_NODES * CH;      // element offset
        uint16_t* W2l = W2h + (size_t)CH * CH;
        k_wcvt<<<(CH * CH + 255) / 256, 256, 0, stream>>>(W2, W2h, W2l);
        const int nb1 = (N_NODES + 63) / 64;   // 1563
        k_w2x_mfma<<<nb1, 256, 0, stream>>>(X, W2h, W2l, Yt);
        const int nb2 = N_NODES / TN;          // 3125
        k_main<<<nb2, 256, 0, stream>>>(X, adj, W1, B1, B2, Yt, Out);
    } else {
        const int nblocks = (N_NODES + 63) / 64;
        k_fused_legacy<<<nblocks, 256, 0, stream>>>(X, adj, W1, B1, W2, B2, Out);
    }
}

// Round 9
// 249.796 us; speedup vs baseline: 1.1635x; 1.1635x over previous
//
#include <hip/hip_runtime.h>
#include <stdint.h>

#define N_NODES 100000
#define CH 128
#define K_NEIGH 16
#define TN 32          // k_main node tile: 100000/32 = 3125 exact
#define XT_STRIDE 36   // k_main X tile stride
#define XS_STRIDE 68   // legacy kernel only
#define PS 132         // pivot stride (node-major [n][o])

#define PSWZ(n, o) ((n) * PS + ((o) ^ ((((n) >> 3) & 3) << 3)))

// ============================================================================
// Round 17. r8 post-mortem: (a) k_main pair-unroll regressed 132->174
// (compiler serialized, FETCH up) -> reverted to r7 gather; (b) kernel-A
// occupancy 2->4 blocks was a no-op -> not TLP-bound. This round halves
// kernel A's serialized work volume: drop the W2hi*Xlo MFMA term.
//  * XsL plane eliminated: staging stores 32 (not 64) scalar b16/thread,
//    LDS 32->16KB, MFMA 96->64/wave, frag reads halved.
//  * Omitted term error ~5e-4 post-mean << bf16-Yt store error (passing).
//  * k_main: exact r7 version (132us, proven r6/r7).
// ============================================================================

typedef short bf8v __attribute__((ext_vector_type(8)));   // 8 bf16 = 4 VGPR
typedef float f32x4 __attribute__((ext_vector_type(4)));

__device__ __forceinline__ uint32_t pack_bf16x2(float a, float b) {
    union { float f; uint32_t u; } ua, ub;
    ua.f = a; ub.f = b;
    const uint32_t ra = (ua.u + 0x7fffu + ((ua.u >> 16) & 1u)) >> 16;
    const uint32_t rb = (ub.u + 0x7fffu + ((ub.u >> 16) & 1u)) >> 16;
    return ra | (rb << 16);
}
__device__ __forceinline__ uint16_t bf16_rne(float f) {
    union { float f; uint32_t u; } c; c.f = f;
    return (uint16_t)((c.u + 0x7fffu + ((c.u >> 16) & 1u)) >> 16);
}
__device__ __forceinline__ float bf16_tof(uint16_t h) {
    union { uint32_t u; float f; } c; c.u = ((uint32_t)h) << 16; return c.f;
}
__device__ __forceinline__ float bf16_lo(uint32_t u) {
    union { uint32_t u; float f; } c; c.u = u << 16; return c.f;
}
__device__ __forceinline__ float bf16_hi(uint32_t u) {
    union { uint32_t u; float f; } c; c.u = u & 0xffff0000u; return c.f;
}

// ---------------------------------------------------------------------------
// Pre-kernel: W2 -> (hi, lo) bf16 planes. 16384 elements.
// ---------------------------------------------------------------------------
__global__ void k_wcvt(const float* __restrict__ W,
                       uint16_t* __restrict__ Wh, uint16_t* __restrict__ Wl) {
    const int i = blockIdx.x * 256 + threadIdx.x;
    if (i < CH * CH) {
        const float f = W[i];
        const uint16_t h = bf16_rne(f);
        Wh[i] = h;
        Wl[i] = bf16_rne(f - bf16_tof(h));
    }
}

// ---------------------------------------------------------------------------
// Kernel 1: Yt[N][CH] = bf16((W2 @ X)^T) via MFMA 16x16x32 bf16.
// W2 split hi/lo (A operand); X hi only (B operand): Y = (W2h+W2l)@Xh.
// 64-node tile, 4 waves; wave w owns o in [32w, 32w+32). 16KB LDS.
// ---------------------------------------------------------------------------
__global__ __launch_bounds__(256, 4) void k_w2x_mfma(
    const float*    __restrict__ X,    // [C][N] f32
    const uint16_t* __restrict__ W2h,  // [o][c] bf16 hi
    const uint16_t* __restrict__ W2l,  // [o][c] bf16 lo
    uint16_t*       __restrict__ Yt)   // [N][CH] bf16
{
    __shared__ __align__(16) uint16_t XsH[64 * 128];  // 16 KB

    const int t  = threadIdx.x;
    const int n0 = blockIdx.x * 64;
    const int V  = (N_NODES - n0 < 64) ? (N_NODES - n0) : 64;

    // ---- stage X: f32 coalesced loads, hi-bf16, transposed swizzled ----
    for (int it = 0; it < 8; ++it) {
        const int idx = t + it * 256;          // 0..2047
        const int nq = idx & 15, c = idx >> 4; // 16 float4-cols, 128 c-rows
        float4 v = make_float4(0.f, 0.f, 0.f, 0.f);
        if (nq * 4 < V)
            v = *(const float4*)&X[(size_t)c * N_NODES + n0 + nq * 4];
        const float vv0 = v.x, vv1 = v.y, vv2 = v.z, vv3 = v.w;
#pragma unroll
        for (int s = 0; s < 4; ++s) {
            const float f = (s == 0) ? vv0 : (s == 1) ? vv1 : (s == 2) ? vv2 : vv3;
            const int n = nq * 4 + s;
            const int byi = (n << 8) + (((c * 2)) ^ ((n & 7) << 4));
            XsH[byi >> 1] = bf16_rne(f);
        }
    }

    // ---- A-frags: W2 hi/lo, loaded once (contiguous dwordx4 per frag) ----
    const int l = t & 63;
    const int w = t >> 6;                 // wave id 0..3
    bf8v ah[2][4], al[2][4];
    const int ar = l & 15;                // A row within 16-tile
    const int ac = (l >> 4) * 8;          // A k-offset
#pragma unroll
    for (int ot = 0; ot < 2; ++ot)
#pragma unroll
        for (int ks = 0; ks < 4; ++ks) {
            const size_t off = (size_t)(w * 32 + ot * 16 + ar) * CH + ks * 32 + ac;
            ah[ot][ks] = *(const bf8v*)&W2h[off];
            al[ot][ks] = *(const bf8v*)&W2l[off];
        }
    __syncthreads();

    // ---- MFMA: D[o][n], 2 o-tiles x 4 n-tiles, K=128 in 4 steps ----
    f32x4 d[2][4];
#pragma unroll
    for (int ot = 0; ot < 2; ++ot)
#pragma unroll
        for (int nt = 0; nt < 4; ++nt)
            d[ot][nt] = (f32x4){0.f, 0.f, 0.f, 0.f};

#pragma unroll
    for (int ks = 0; ks < 4; ++ks) {
#pragma unroll
        for (int nt = 0; nt < 4; ++nt) {
            const int n  = nt * 16 + (l & 15);
            const int byi = (n << 8) + ((ks * 64 + ((l >> 4) * 16)) ^ ((n & 7) << 4));
            const bf8v bh = *(const bf8v*)((const char*)XsH + byi);
#pragma unroll
            for (int ot = 0; ot < 2; ++ot) {
                d[ot][nt] = __builtin_amdgcn_mfma_f32_16x16x32_bf16(
                    ah[ot][ks], bh, d[ot][nt], 0, 0, 0);
                d[ot][nt] = __builtin_amdgcn_mfma_f32_16x16x32_bf16(
                    al[ot][ks], bh, d[ot][nt], 0, 0, 0);
            }
        }
    }

    // ---- store: lane holds o = base+(l>>4)*4+r, n = nt*16+(l&15) ----
#pragma unroll
    for (int ot = 0; ot < 2; ++ot)
#pragma unroll
        for (int nt = 0; nt < 4; ++nt) {
            const int n = nt * 16 + (l & 15);
            if (n < V) {
                const int o4 = w * 32 + ot * 16 + (l >> 4) * 4;
                uint2 pv;
                pv.x = pack_bf16x2(d[ot][nt][0], d[ot][nt][1]);
                pv.y = pack_bf16x2(d[ot][nt][2], d[ot][nt][3]);
                *(uint2*)&Yt[(size_t)(n0 + n) * CH + o4] = pv;
            }
        }
}

// ---------------------------------------------------------------------------
// Kernel 2 (r7 audited, 132us): Out = W1@X + mean_k bf16(Yt)[adj] + biases.
// ---------------------------------------------------------------------------
__global__ __launch_bounds__(256, 8) void k_main(
    const float*    __restrict__ X,    // [C][N] f32
    const int*      __restrict__ adj,  // [N][K] int32
    const float*    __restrict__ W1,   // [o][c] f32
    const float*    __restrict__ B1,
    const float*    __restrict__ B2,
    const uint16_t* __restrict__ Yt,   // [N][CH] bf16
    float*          __restrict__ Out)  // [O][N] f32
{
    __shared__ __align__(16) float Xs[CH * XT_STRIDE];
    __shared__ __align__(16) int adjS[TN * K_NEIGH];

    const int t  = threadIdx.x;
    const int n0 = blockIdx.x * TN;

    if (t < 128)
        *(int4*)&adjS[t * 4] = *(const int4*)&adj[(size_t)n0 * K_NEIGH + t * 4];
    for (int it = 0; it < 4; ++it) {
        const int idx = t + it * 256;
        const int nq = idx & 7, c = idx >> 3;
        *(float4*)&Xs[c * XT_STRIDE + nq * 4] =
            *(const float4*)&X[(size_t)c * N_NODES + n0 + nq * 4];
    }
    __syncthreads();

    const int ng = t & 7, og = t >> 3;
    float acc[4][4];
#pragma unroll
    for (int i = 0; i < 4; ++i)
#pragma unroll
        for (int j = 0; j < 4; ++j) acc[i][j] = 0.0f;

    const float* wp = W1 + (size_t)(og * 4) * CH;
#pragma unroll 1
    for (int c0 = 0; c0 < CH; c0 += 4) {
        float4 wq[4];
#pragma unroll
        for (int i = 0; i < 4; ++i)
            wq[i] = *(const float4*)&wp[i * CH + c0];
#pragma unroll
        for (int e = 0; e < 4; ++e) {
            const float4 xv = *(const float4*)&Xs[(c0 + e) * XT_STRIDE + ng * 4];
#pragma unroll
            for (int i = 0; i < 4; ++i) {
                const float w = ((const float*)&wq[i])[e];
                acc[i][0] = fmaf(w, xv.x, acc[i][0]);
                acc[i][1] = fmaf(w, xv.y, acc[i][1]);
                acc[i][2] = fmaf(w, xv.z, acc[i][2]);
                acc[i][3] = fmaf(w, xv.w, acc[i][3]);
            }
        }
    }

    __syncthreads();
    float* P = Xs;
#pragma unroll
    for (int j = 0; j < 4; ++j) {
        const int n = ng * 4 + j;
        float4 v = make_float4(acc[0][j], acc[1][j], acc[2][j], acc[3][j]);
        *(float4*)&P[PSWZ(n, og * 4)] = v;
    }
    __syncthreads();

    // ---- gather-mean from bf16 Yt, RMW into P (r6/r7 audited) ----
    {
        const int l4 = (t & 31) * 4;
        const int g  = t >> 5;
        for (int itp = 0; itp < 4; ++itp) {
            const int n = itp * 8 + g;
            int js[K_NEIGH];
#pragma unroll
            for (int k = 0; k < K_NEIGH; ++k) js[k] = adjS[n * K_NEIGH + k];
            float4 a0 = make_float4(0.f, 0.f, 0.f, 0.f);
            float4 a1 = make_float4(0.f, 0.f, 0.f, 0.f);
#pragma unroll
            for (int k = 0; k < K_NEIGH; k += 2) {
                const uint2 v0 = *(const uint2*)&Yt[(size_t)js[k]     * CH + l4];
                const uint2 v1 = *(const uint2*)&Yt[(size_t)js[k + 1] * CH + l4];
                a0.x += bf16_lo(v0.x); a0.y += bf16_hi(v0.x);
                a0.z += bf16_lo(v0.y); a0.w += bf16_hi(v0.y);
                a1.x += bf16_lo(v1.x); a1.y += bf16_hi(v1.x);
                a1.z += bf16_lo(v1.y); a1.w += bf16_hi(v1.y);
            }
            float4 cur = *(const float4*)&P[PSWZ(n, l4)];
            cur.x += (a0.x + a1.x) * 0.0625f;
            cur.y += (a0.y + a1.y) * 0.0625f;
            cur.z += (a0.z + a1.z) * 0.0625f;
            cur.w += (a0.w + a1.w) * 0.0625f;
            *(float4*)&P[PSWZ(n, l4)] = cur;
        }
    }
    __syncthreads();

    for (int it = 0; it < 4; ++it) {
        const int idx = t + it * 256;
        const int o = idx >> 3, nq = idx & 7;
        const float bb = B1[o] + B2[o];
        float4 v;
        v.x = P[PSWZ(nq * 4 + 0, o)] + bb;
        v.y = P[PSWZ(nq * 4 + 1, o)] + bb;
        v.z = P[PSWZ(nq * 4 + 2, o)] + bb;
        v.w = P[PSWZ(nq * 4 + 3, o)] + bb;
        *(float4*)&Out[(size_t)o * N_NODES + n0 + nq * 4] = v;
    }
}

// ---------------------------------------------------------------------------
// Legacy fused kernel (audited) -- fallback if workspace too small.
// ---------------------------------------------------------------------------
__global__ __launch_bounds__(256, 2) void k_fused_legacy(
    const float* __restrict__ X,
    const int*   __restrict__ adj,
    const float* __restrict__ W1,
    const float* __restrict__ B1,
    const float* __restrict__ W2,
    const float* __restrict__ B2,
    float*       __restrict__ Out)
{
    __shared__ __align__(16) float Xs[CH * XS_STRIDE];
    __shared__ __align__(16) float As[CH * XS_STRIDE];
    __shared__ int adjS[64 * K_NEIGH];

    const int t  = threadIdx.x;
    const int n0 = blockIdx.x * 64;
    const int V  = (N_NODES - n0 < 64) ? (N_NODES - n0) : 64;

    {
        const int base  = n0 * K_NEIGH;
        const int valid = V * K_NEIGH;
        for (int idx = t; idx < 64 * K_NEIGH; idx += 256)
            adjS[idx] = (idx < valid) ? adj[base + idx] : 0;
    }
    for (int it = 0; it < 32; ++it) {
        const int idx = t + it * 256;
        const int n = idx & 63, c = idx >> 6;
        Xs[c * XS_STRIDE + n] =
            (n < V) ? X[(size_t)c * N_NODES + n0 + n] : 0.0f;
    }
    __syncthreads();

    {
        const int n_l = t & 63, q = t >> 6;
        int js[K_NEIGH];
#pragma unroll
        for (int k = 0; k < K_NEIGH; ++k) js[k] = adjS[n_l * K_NEIGH + k];
        if (n_l < V) {
            for (int cc = 0; cc < 32; ++cc) {
                const int c = q * 32 + cc;
                const float* xc = X + (size_t)c * N_NODES;
                float s = 0.0f;
#pragma unroll
                for (int k = 0; k < K_NEIGH; ++k) s += xc[js[k]];
                As[c * XS_STRIDE + n_l] = s * 0.0625f;
            }
        } else {
            for (int cc = 0; cc < 32; ++cc)
                As[(q * 32 + cc) * XS_STRIDE + n_l] = 0.0f;
        }
    }
    __syncthreads();

    const int ng = t & 7, og = t >> 3;
    float acc[4][8];
#pragma unroll
    for (int i = 0; i < 4; ++i)
#pragma unroll
        for (int j = 0; j < 8; ++j) acc[i][j] = 0.0f;

    const float* w1p = W1 + (og * 4) * CH;
    const float* w2p = W2 + (og * 4) * CH;
    for (int c = 0; c < CH; ++c) {
        float xv[8], av[8], w1v[4], w2v[4];
        *(float4*)&xv[0] = *(const float4*)&Xs[c * XS_STRIDE + ng * 8];
        *(float4*)&xv[4] = *(const float4*)&Xs[c * XS_STRIDE + ng * 8 + 4];
        *(float4*)&av[0] = *(const float4*)&As[c * XS_STRIDE + ng * 8];
        *(float4*)&av[4] = *(const float4*)&As[c * XS_STRIDE + ng * 8 + 4];
#pragma unroll
        for (int i = 0; i < 4; ++i) {
            w1v[i] = w1p[i * CH + c];
            w2v[i] = w2p[i * CH + c];
        }
#pragma unroll
        for (int i = 0; i < 4; ++i)
#pragma unroll
            for (int j = 0; j < 8; ++j)
                acc[i][j] += w1v[i] * xv[j] + w2v[i] * av[j];
    }

    __syncthreads();
    float* Zt = Xs;
#pragma unroll
    for (int i = 0; i < 4; ++i) {
        *(float4*)&Zt[(og * 4 + i) * XS_STRIDE + ng * 8]     = *(float4*)&acc[i][0];
        *(float4*)&Zt[(og * 4 + i) * XS_STRIDE + ng * 8 + 4] = *(float4*)&acc[i][4];
    }
    __syncthreads();
    for (int it = 0; it < 32; ++it) {
        const int idx = t + it * 256;
        const int n = idx & 63, o = idx >> 6;
        if (n < V) {
            Out[(size_t)o * N_NODES + n0 + n] =
                Zt[o * XS_STRIDE + n] + B1[o] + B2[o];
        }
    }
}

extern "C" void kernel_launch(void* const* d_in, const int* in_sizes, int n_in,
                              void* d_out, int out_size, void* d_ws, size_t ws_size,
                              hipStream_t stream) {
    const float* X   = (const float*)d_in[0];
    const int*   adj = (const int*)d_in[1];
    const float* W1  = (const float*)d_in[2];
    const float* B1  = (const float*)d_in[3];
    const float* W2  = (const float*)d_in[4];
    const float* B2  = (const float*)d_in[5];
    float* Out = (float*)d_out;

    const size_t yt_bytes = (size_t)N_NODES * CH * sizeof(uint16_t);  // 25.6 MB
    const size_t w_bytes  = (size_t)CH * CH * sizeof(uint16_t);       // 32 KB
    const size_t need     = yt_bytes + 2 * w_bytes;

    if (ws_size >= need) {
        uint16_t* Yt  = (uint16_t*)d_ws;
        uint16_t* W2h = Yt + (size_t)N_NODES * CH;      // element offset
        uint16_t* W2l = W2h + (size_t)CH * CH;
        k_wcvt<<<(CH * CH + 255) / 256, 256, 0, stream>>>(W2, W2h, W2l);
        const int nb1 = (N_NODES + 63) / 64;   // 1563
        k_w2x_mfma<<<nb1, 256, 0, stream>>>(X, W2h, W2l, Yt);
        const int nb2 = N_NODES / TN;          // 3125
        k_main<<<nb2, 256, 0, stream>>>(X, adj, W1, B1, B2, Yt, Out);
    } else {
        const int nblocks = (N_NODES + 63) / 64;
        k_fused_legacy<<<nblocks, 256, 0, stream>>>(X, adj, W1, B1, W2, B2, Out);
    }
}

// Round 10
// 236.761 us; speedup vs baseline: 1.2276x; 1.0551x over previous
//
#include <hip/hip_runtime.h>
#include <stdint.h>

#define N_NODES 100000
#define CH 128
#define K_NEIGH 16
#define TN 32          // k_gather node tile: 100000/32 = 3125 exact
#define XS_STRIDE 68   // legacy kernel only
#define PS 132         // pivot stride (node-major [n][o])

#define PSWZ(n, o) ((n) * PS + ((o) ^ ((((n) >> 3) & 3) << 3)))

// ============================================================================
// Round 18. r9 evidence: kernel A (~115us) is insensitive to staging volume,
// MFMA count, LDS, occupancy -- AND has never appeared in the top-5 counter
// rows (k_main fills them). Restructure to unblind + amortize:
//  * k_dual: one X staging pass -> BOTH GEMMs via MFMA.
//      Out = (W1h+W1l)@Xh + W1h@Xl + biases   (f32-grade direct path)
//      Yt  = bf16((W2h+W2l)@Xh)               (r9-audited gather path)
//    W-frags loaded per-ks (32 VGPR live, not 128 -- r4 spill lesson).
//  * k_gather: pure gather + float4 RMW into Out. 19KB LDS, 8 blocks/CU,
//    no GEMM/pivot on its critical path (r4 structure + bf16 + PSWZ).
//  * Both kernels now land in top-5 -> counters for the mystery kernel.
// ============================================================================

typedef short bf8v __attribute__((ext_vector_type(8)));   // 8 bf16 = 4 VGPR
typedef float f32x4 __attribute__((ext_vector_type(4)));

__device__ __forceinline__ uint32_t pack_bf16x2(float a, float b) {
    union { float f; uint32_t u; } ua, ub;
    ua.f = a; ub.f = b;
    const uint32_t ra = (ua.u + 0x7fffu + ((ua.u >> 16) & 1u)) >> 16;
    const uint32_t rb = (ub.u + 0x7fffu + ((ub.u >> 16) & 1u)) >> 16;
    return ra | (rb << 16);
}
__device__ __forceinline__ uint16_t bf16_rne(float f) {
    union { float f; uint32_t u; } c; c.f = f;
    return (uint16_t)((c.u + 0x7fffu + ((c.u >> 16) & 1u)) >> 16);
}
__device__ __forceinline__ float bf16_tof(uint16_t h) {
    union { uint32_t u; float f; } c; c.u = ((uint32_t)h) << 16; return c.f;
}
__device__ __forceinline__ float bf16_lo(uint32_t u) {
    union { uint32_t u; float f; } c; c.u = u << 16; return c.f;
}
__device__ __forceinline__ float bf16_hi(uint32_t u) {
    union { uint32_t u; float f; } c; c.u = u & 0xffff0000u; return c.f;
}

// ---------------------------------------------------------------------------
// Pre-kernel: W -> (hi, lo) bf16 planes. Launched once per weight matrix.
// ---------------------------------------------------------------------------
__global__ void k_wcvt(const float* __restrict__ W,
                       uint16_t* __restrict__ Wh, uint16_t* __restrict__ Wl) {
    const int i = blockIdx.x * 256 + threadIdx.x;
    if (i < CH * CH) {
        const float f = W[i];
        const uint16_t h = bf16_rne(f);
        Wh[i] = h;
        Wl[i] = bf16_rne(f - bf16_tof(h));
    }
}

// ---------------------------------------------------------------------------
// Kernel 1: k_dual. 64-node tile, 4 waves; wave w owns o in [32w, 32w+32).
//   Out[o][n] = D1 + B1[o] + B2[o],  D1 = (W1h+W1l)@Xh + W1h@Xl
//   Yt[n][o]  = bf16(D2),            D2 = (W2h+W2l)@Xh
// LDS: XsH + XsL, 16KB each. Frag layouts per guide (m89).
// ---------------------------------------------------------------------------
__global__ __launch_bounds__(256, 2) void k_dual(
    const float*    __restrict__ X,    // [C][N] f32
    const uint16_t* __restrict__ W1h,
    const uint16_t* __restrict__ W1l,
    const uint16_t* __restrict__ W2h,
    const uint16_t* __restrict__ W2l,
    const float*    __restrict__ B1,
    const float*    __restrict__ B2,
    uint16_t*       __restrict__ Yt,   // [N][CH] bf16
    float*          __restrict__ Out)  // [O][N] f32
{
    __shared__ __align__(16) uint16_t XsH[64 * 128];  // 16 KB
    __shared__ __align__(16) uint16_t XsL[64 * 128];  // 16 KB

    const int t  = threadIdx.x;
    const int n0 = blockIdx.x * 64;
    const int V  = (N_NODES - n0 < 64) ? (N_NODES - n0) : 64;

    // ---- stage X: f32 coalesced loads, hi/lo bf16, transposed swizzled ----
    for (int it = 0; it < 8; ++it) {
        const int idx = t + it * 256;          // 0..2047
        const int nq = idx & 15, c = idx >> 4;
        float4 v = make_float4(0.f, 0.f, 0.f, 0.f);
        if (nq * 4 < V)
            v = *(const float4*)&X[(size_t)c * N_NODES + n0 + nq * 4];
        const float vv0 = v.x, vv1 = v.y, vv2 = v.z, vv3 = v.w;
#pragma unroll
        for (int s = 0; s < 4; ++s) {
            const float f = (s == 0) ? vv0 : (s == 1) ? vv1 : (s == 2) ? vv2 : vv3;
            const int n = nq * 4 + s;
            const int byi = (n << 8) + (((c * 2)) ^ ((n & 7) << 4));
            const uint16_t h = bf16_rne(f);
            XsH[byi >> 1] = h;
            XsL[byi >> 1] = bf16_rne(f - bf16_tof(h));
        }
    }
    __syncthreads();

    const int l = t & 63;
    const int w = t >> 6;                 // wave id 0..3
    const int ar = l & 15;                // A row within 16-tile
    const int ac = (l >> 4) * 8;          // A k-offset

    f32x4 d1[2][4], d2[2][4];
#pragma unroll
    for (int ot = 0; ot < 2; ++ot)
#pragma unroll
        for (int nt = 0; nt < 4; ++nt) {
            d1[ot][nt] = (f32x4){0.f, 0.f, 0.f, 0.f};
            d2[ot][nt] = (f32x4){0.f, 0.f, 0.f, 0.f};
        }

#pragma unroll
    for (int ks = 0; ks < 4; ++ks) {
        // W-frags for this ks only: 8 x 16B loads, 32 VGPR live
        bf8v a1h[2], a1l[2], a2h[2], a2l[2];
#pragma unroll
        for (int ot = 0; ot < 2; ++ot) {
            const size_t off = (size_t)(w * 32 + ot * 16 + ar) * CH + ks * 32 + ac;
            a1h[ot] = *(const bf8v*)&W1h[off];
            a1l[ot] = *(const bf8v*)&W1l[off];
            a2h[ot] = *(const bf8v*)&W2h[off];
            a2l[ot] = *(const bf8v*)&W2l[off];
        }
#pragma unroll
        for (int nt = 0; nt < 4; ++nt) {
            const int n  = nt * 16 + (l & 15);
            const int byi = (n << 8) + ((ks * 64 + ((l >> 4) * 16)) ^ ((n & 7) << 4));
            const bf8v bh = *(const bf8v*)((const char*)XsH + byi);
            const bf8v bl = *(const bf8v*)((const char*)XsL + byi);
#pragma unroll
            for (int ot = 0; ot < 2; ++ot) {
                d1[ot][nt] = __builtin_amdgcn_mfma_f32_16x16x32_bf16(
                    a1h[ot], bh, d1[ot][nt], 0, 0, 0);
                d1[ot][nt] = __builtin_amdgcn_mfma_f32_16x16x32_bf16(
                    a1l[ot], bh, d1[ot][nt], 0, 0, 0);
                d1[ot][nt] = __builtin_amdgcn_mfma_f32_16x16x32_bf16(
                    a1h[ot], bl, d1[ot][nt], 0, 0, 0);
                d2[ot][nt] = __builtin_amdgcn_mfma_f32_16x16x32_bf16(
                    a2h[ot], bh, d2[ot][nt], 0, 0, 0);
                d2[ot][nt] = __builtin_amdgcn_mfma_f32_16x16x32_bf16(
                    a2l[ot], bh, d2[ot][nt], 0, 0, 0);
            }
        }
    }

    // ---- Out stores: D1 + biases. Per instr: 4 o-rows x 64B segments ----
#pragma unroll
    for (int ot = 0; ot < 2; ++ot) {
        const int ob = w * 32 + ot * 16 + (l >> 4) * 4;
        const float b0 = B1[ob + 0] + B2[ob + 0];
        const float b1 = B1[ob + 1] + B2[ob + 1];
        const float b2 = B1[ob + 2] + B2[ob + 2];
        const float b3 = B1[ob + 3] + B2[ob + 3];
#pragma unroll
        for (int nt = 0; nt < 4; ++nt) {
            const int n = nt * 16 + (l & 15);
            if (n < V) {
                float* op = Out + (size_t)ob * N_NODES + n0 + n;
                op[0]                   = d1[ot][nt][0] + b0;
                op[(size_t)N_NODES]     = d1[ot][nt][1] + b1;
                op[(size_t)N_NODES * 2] = d1[ot][nt][2] + b2;
                op[(size_t)N_NODES * 3] = d1[ot][nt][3] + b3;
            }
        }
    }

    // ---- Yt stores: bf16(D2), 8B per (ot,nt) ----
#pragma unroll
    for (int ot = 0; ot < 2; ++ot)
#pragma unroll
        for (int nt = 0; nt < 4; ++nt) {
            const int n = nt * 16 + (l & 15);
            if (n < V) {
                const int o4 = w * 32 + ot * 16 + (l >> 4) * 4;
                uint2 pv;
                pv.x = pack_bf16x2(d2[ot][nt][0], d2[ot][nt][1]);
                pv.y = pack_bf16x2(d2[ot][nt][2], d2[ot][nt][3]);
                *(uint2*)&Yt[(size_t)(n0 + n) * CH + o4] = pv;
            }
        }
}

// ---------------------------------------------------------------------------
// Kernel 2: k_gather. Out[o][n] += mean_k bf16(Yt)[adj[n][k]][o].
// 32-node tiles, 19KB LDS, 8 blocks/CU. Gather inner loop r7-audited.
// Idempotent across replays: k_dual rewrites Out first each replay.
// ---------------------------------------------------------------------------
__global__ __launch_bounds__(256, 8) void k_gather(
    const int*      __restrict__ adj,  // [N][K] int32
    const uint16_t* __restrict__ Yt,   // [N][CH] bf16
    float*          __restrict__ Out)  // [O][N] f32
{
    __shared__ __align__(16) float P[TN * PS];        // 16.9 KB
    __shared__ __align__(16) int adjS[TN * K_NEIGH];  // 2 KB

    const int t  = threadIdx.x;
    const int n0 = blockIdx.x * TN;   // exact tiles

    if (t < 128)
        *(int4*)&adjS[t * 4] = *(const int4*)&adj[(size_t)n0 * K_NEIGH + t * 4];
    __syncthreads();

    // ---- gather-mean: 8 groups of 32 lanes; lane owns 4 channels ----
    {
        const int l4 = (t & 31) * 4;
        const int g  = t >> 5;
        for (int itp = 0; itp < 4; ++itp) {
            const int n = itp * 8 + g;
            int js[K_NEIGH];
#pragma unroll
            for (int k = 0; k < K_NEIGH; ++k) js[k] = adjS[n * K_NEIGH + k];
            float4 a0 = make_float4(0.f, 0.f, 0.f, 0.f);
            float4 a1 = make_float4(0.f, 0.f, 0.f, 0.f);
#pragma unroll
            for (int k = 0; k < K_NEIGH; k += 2) {
                const uint2 v0 = *(const uint2*)&Yt[(size_t)js[k]     * CH + l4];
                const uint2 v1 = *(const uint2*)&Yt[(size_t)js[k + 1] * CH + l4];
                a0.x += bf16_lo(v0.x); a0.y += bf16_hi(v0.x);
                a0.z += bf16_lo(v0.y); a0.w += bf16_hi(v0.y);
                a1.x += bf16_lo(v1.x); a1.y += bf16_hi(v1.x);
                a1.z += bf16_lo(v1.y); a1.w += bf16_hi(v1.y);
            }
            float4 s;
            s.x = (a0.x + a1.x) * 0.0625f;
            s.y = (a0.y + a1.y) * 0.0625f;
            s.z = (a0.z + a1.z) * 0.0625f;
            s.w = (a0.w + a1.w) * 0.0625f;
            *(float4*)&P[PSWZ(n, l4)] = s;   // contiguous 128B/group
        }
    }
    __syncthreads();

    // ---- RMW epilogue: Out[o][n0..n0+32) += P; float4 along n ----
    for (int it = 0; it < 4; ++it) {
        const int idx = t + it * 256;          // 0..1023
        const int o = idx >> 3, nq = idx & 7;
        float* op = Out + (size_t)o * N_NODES + n0 + nq * 4;
        float4 cur = *(const float4*)op;
        cur.x += P[PSWZ(nq * 4 + 0, o)];
        cur.y += P[PSWZ(nq * 4 + 1, o)];
        cur.z += P[PSWZ(nq * 4 + 2, o)];
        cur.w += P[PSWZ(nq * 4 + 3, o)];
        *(float4*)op = cur;
    }
}

// ---------------------------------------------------------------------------
// Legacy fused kernel (audited) -- fallback if workspace too small.
// ---------------------------------------------------------------------------
__global__ __launch_bounds__(256, 2) void k_fused_legacy(
    const float* __restrict__ X,
    const int*   __restrict__ adj,
    const float* __restrict__ W1,
    const float* __restrict__ B1,
    const float* __restrict__ W2,
    const float* __restrict__ B2,
    float*       __restrict__ Out)
{
    __shared__ __align__(16) float Xs[CH * XS_STRIDE];
    __shared__ __align__(16) float As[CH * XS_STRIDE];
    __shared__ int adjS[64 * K_NEIGH];

    const int t  = threadIdx.x;
    const int n0 = blockIdx.x * 64;
    const int V  = (N_NODES - n0 < 64) ? (N_NODES - n0) : 64;

    {
        const int base  = n0 * K_NEIGH;
        const int valid = V * K_NEIGH;
        for (int idx = t; idx < 64 * K_NEIGH; idx += 256)
            adjS[idx] = (idx < valid) ? adj[base + idx] : 0;
    }
    for (int it = 0; it < 32; ++it) {
        const int idx = t + it * 256;
        const int n = idx & 63, c = idx >> 6;
        Xs[c * XS_STRIDE + n] =
            (n < V) ? X[(size_t)c * N_NODES + n0 + n] : 0.0f;
    }
    __syncthreads();

    {
        const int n_l = t & 63, q = t >> 6;
        int js[K_NEIGH];
#pragma unroll
        for (int k = 0; k < K_NEIGH; ++k) js[k] = adjS[n_l * K_NEIGH + k];
        if (n_l < V) {
            for (int cc = 0; cc < 32; ++cc) {
                const int c = q * 32 + cc;
                const float* xc = X + (size_t)c * N_NODES;
                float s = 0.0f;
#pragma unroll
                for (int k = 0; k < K_NEIGH; ++k) s += xc[js[k]];
                As[c * XS_STRIDE + n_l] = s * 0.0625f;
            }
        } else {
            for (int cc = 0; cc < 32; ++cc)
                As[(q * 32 + cc) * XS_STRIDE + n_l] = 0.0f;
        }
    }
    __syncthreads();

    const int ng = t & 7, og = t >> 3;
    float acc[4][8];
#pragma unroll
    for (int i = 0; i < 4; ++i)
#pragma unroll
        for (int j = 0; j < 8; ++j) acc[i][j] = 0.0f;

    const float* w1p = W1 + (og * 4) * CH;
    const float* w2p = W2 + (og * 4) * CH;
    for (int c = 0; c < CH; ++c) {
        float xv[8], av[8], w1v[4], w2v[4];
        *(float4*)&xv[0] = *(const float4*)&Xs[c * XS_STRIDE + ng * 8];
        *(float4*)&xv[4] = *(const float4*)&Xs[c * XS_STRIDE + ng * 8 + 4];
        *(float4*)&av[0] = *(const float4*)&As[c * XS_STRIDE + ng * 8];
        *(float4*)&av[4] = *(const float4*)&As[c * XS_STRIDE + ng * 8 + 4];
#pragma unroll
        for (int i = 0; i < 4; ++i) {
            w1v[i] = w1p[i * CH + c];
            w2v[i] = w2p[i * CH + c];
        }
#pragma unroll
        for (int i = 0; i < 4; ++i)
#pragma unroll
            for (int j = 0; j < 8; ++j)
                acc[i][j] += w1v[i] * xv[j] + w2v[i] * av[j];
    }

    __syncthreads();
    float* Zt = Xs;
#pragma unroll
    for (int i = 0; i < 4; ++i) {
        *(float4*)&Zt[(og * 4 + i) * XS_STRIDE + ng * 8]     = *(float4*)&acc[i][0];
        *(float4*)&Zt[(og * 4 + i) * XS_STRIDE + ng * 8 + 4] = *(float4*)&acc[i][4];
    }
    __syncthreads();
    for (int it = 0; it < 32; ++it) {
        const int idx = t + it * 256;
        const int n = idx & 63, o = idx >> 6;
        if (n < V) {
            Out[(size_t)o * N_NODES + n0 + n] =
                Zt[o * XS_STRIDE + n] + B1[o] + B2[o];
        }
    }
}

extern "C" void kernel_launch(void* const* d_in, const int* in_sizes, int n_in,
                              void* d_out, int out_size, void* d_ws, size_t ws_size,
                              hipStream_t stream) {
    const float* X   = (const float*)d_in[0];
    const int*   adj = (const int*)d_in[1];
    const float* W1  = (const float*)d_in[2];
    const float* B1  = (const float*)d_in[3];
    const float* W2  = (const float*)d_in[4];
    const float* B2  = (const float*)d_in[5];
    float* Out = (float*)d_out;

    const size_t yt_elems = (size_t)N_NODES * CH;           // 12.8 M
    const size_t w_elems  = (size_t)CH * CH;                // 16384
    const size_t need = (yt_elems + 4 * w_elems) * sizeof(uint16_t);  // ~25.7 MB

    if (ws_size >= need) {
        uint16_t* Yt  = (uint16_t*)d_ws;
        uint16_t* W1h = Yt + yt_elems;
        uint16_t* W1l = W1h + w_elems;
        uint16_t* W2h = W1l + w_elems;
        uint16_t* W2l = W2h + w_elems;
        const int wcb = (CH * CH + 255) / 256;
        k_wcvt<<<wcb, 256, 0, stream>>>(W1, W1h, W1l);
        k_wcvt<<<wcb, 256, 0, stream>>>(W2, W2h, W2l);
        const int nb1 = (N_NODES + 63) / 64;   // 1563
        k_dual<<<nb1, 256, 0, stream>>>(X, W1h, W1l, W2h, W2l, B1, B2, Yt, Out);
        const int nb2 = N_NODES / TN;          // 3125
        k_gather<<<nb2, 256, 0, stream>>>(adj, Yt, Out);
    } else {
        const int nblocks = (N_NODES + 63) / 64;
        k_fused_legacy<<<nblocks, 256, 0, stream>>>(X, adj, W1, B1, W2, B2, Out);
    }
}